// Round 1
// baseline (7299.526 us; speedup 1.0000x reference)
//
#include <hip/hip_runtime.h>
#include <hip/hip_bf16.h>
#include <math.h>

#define N_PATHS  200000
#define PATH_LEN 8
#define N_LINKS  20000
#define MAX_PL   100
#define DIM      16
#define ITERS    8

// workspace layout (bytes):
//   seq : float[9][N_PATHS][DIM]   = 115,200,000   (path_state_sequence; slot 8 = current path_state)
//   ls  : float[N_LINKS][DIM]      =   1,280,000   (link_state)
//   lxk : float[N_LINKS][48]       =   3,840,000   (link_state @ pgru_k + pgru_b[0])
#define SEQ_BYTES 115200000ull
#define LS_BYTES  1280000ull

__device__ __forceinline__ float sigmoidf_(float x) {
    return 1.0f / (1.0f + expf(-x));
}
__device__ __forceinline__ float softplusf_(float x) {
    return fmaxf(x, 0.0f) + log1pf(expf(-fabsf(x)));
}

// ---------------- init: link load -> link_state -> lxk ----------------
__global__ __launch_bounds__(64) void k_init_links(
    const float* __restrict__ traffic, const float* __restrict__ cap,
    const int* __restrict__ p2l,
    const float* __restrict__ le_w1, const float* __restrict__ le_b1,
    const float* __restrict__ le_w2, const float* __restrict__ le_b2,
    const float* __restrict__ pk, const float* __restrict__ pb,
    float* __restrict__ ls, float* __restrict__ lxk)
{
    int l = blockIdx.x;
    int lane = threadIdx.x;
    float s = 0.0f;
    for (int j = lane; j < MAX_PL; j += 64) {
        int p = p2l[(size_t)(l * MAX_PL + j) * 2 + 0];
        s += traffic[p];
    }
    #pragma unroll
    for (int off = 32; off > 0; off >>= 1) s += __shfl_xor(s, off);

    float c = cap[l];
    float f0 = c * 0.1f;
    float f1 = s / (c * 1e9f);

    float h1[DIM];
    #pragma unroll
    for (int d = 0; d < DIM; d++)
        h1[d] = fmaxf(f0 * le_w1[d] + f1 * le_w1[DIM + d] + le_b1[d], 0.0f);

    float h2[DIM];
    #pragma unroll
    for (int d = 0; d < DIM; d++) {
        float a = le_b2[d];
        #pragma unroll
        for (int k = 0; k < DIM; k++) a = fmaf(h1[k], le_w2[k * DIM + d], a);
        h2[d] = fmaxf(a, 0.0f);
    }
    if (lane < DIM) ls[(size_t)l * DIM + lane] = h2[lane];
    if (lane < 48) {
        float a = pb[lane];
        #pragma unroll
        for (int k = 0; k < DIM; k++) a = fmaf(h2[k], pk[k * 48 + lane], a);
        lxk[(size_t)l * 48 + lane] = a;
    }
}

// ---------------- init: path_state -> seq[8] ----------------
__global__ __launch_bounds__(256) void k_init_paths(
    const float* __restrict__ traffic, const float* __restrict__ packets,
    const float* __restrict__ pktsize, const float* __restrict__ ftype,
    const float* __restrict__ fe_w1, const float* __restrict__ fe_b1,
    const float* __restrict__ fe_w2, const float* __restrict__ fe_b2,
    float* __restrict__ seq)
{
    int p = blockIdx.x * blockDim.x + threadIdx.x;
    if (p >= N_PATHS) return;
    float f[5];
    f[0] = traffic[p] * 0.0001f;
    f[1] = packets[p] * 0.01f;
    f[2] = pktsize[p] * 0.001f;
    f[3] = ftype[p * 2 + 0];
    f[4] = ftype[p * 2 + 1];

    float h1[DIM];
    #pragma unroll
    for (int d = 0; d < DIM; d++) {
        float a = fe_b1[d];
        #pragma unroll
        for (int k = 0; k < 5; k++) a = fmaf(f[k], fe_w1[k * DIM + d], a);
        h1[d] = fmaxf(a, 0.0f);
    }
    float* out = seq + ((size_t)8 * N_PATHS + p) * DIM;
    #pragma unroll
    for (int d = 0; d < DIM; d++) {
        float a = fe_b2[d];
        #pragma unroll
        for (int k = 0; k < DIM; k++) a = fmaf(h1[k], fe_w2[k * DIM + d], a);
        out[d] = fmaxf(a, 0.0f);
    }
}

// ---------------- per-iteration: path GRU over 8 steps ----------------
__global__ __launch_bounds__(256) void k_paths(
    const int* __restrict__ l2p, const float* __restrict__ lxk,
    const float* __restrict__ rk, const float* __restrict__ b,
    float* __restrict__ seq)
{
    int p = blockIdx.x * blockDim.x + threadIdx.x;
    if (p >= N_PATHS) return;

    float h[DIM];
    {
        const float* hp = seq + ((size_t)8 * N_PATHS + p) * DIM;
        #pragma unroll
        for (int d = 0; d < DIM; d++) h[d] = hp[d];
        float* s0 = seq + (size_t)p * DIM;  // entry 0 = prev
        #pragma unroll
        for (int d = 0; d < DIM; d++) s0[d] = h[d];
    }

    for (int t = 0; t < PATH_LEN; t++) {
        int li = l2p[(size_t)p * PATH_LEN + t];
        const float* x = lxk + (size_t)li * 48;
        float mx[48];
        #pragma unroll
        for (int j = 0; j < 48; j++) mx[j] = x[j];

        float mi[48];
        #pragma unroll
        for (int j = 0; j < 48; j++) mi[j] = b[48 + j];
        #pragma unroll
        for (int k = 0; k < DIM; k++) {
            float hk = h[k];
            #pragma unroll
            for (int j = 0; j < 48; j++) mi[j] = fmaf(hk, rk[k * 48 + j], mi[j]);
        }

        #pragma unroll
        for (int d = 0; d < DIM; d++) {
            float z  = sigmoidf_(mx[d] + mi[d]);
            float r  = sigmoidf_(mx[16 + d] + mi[16 + d]);
            float hh = tanhf(mx[32 + d] + r * mi[32 + d]);
            h[d] = z * h[d] + (1.0f - z) * hh;
        }

        float* so = seq + ((size_t)(t + 1) * N_PATHS + p) * DIM;
        #pragma unroll
        for (int d = 0; d < DIM; d++) so[d] = h[d];
    }
}

// ---------------- per-iteration: link aggregate + link GRU + lxk ----------------
__global__ __launch_bounds__(64) void k_links(
    const int* __restrict__ p2l, const float* __restrict__ seq,
    const float* __restrict__ lk, const float* __restrict__ lrk,
    const float* __restrict__ lb,
    const float* __restrict__ pk, const float* __restrict__ pb,
    float* ls, float* __restrict__ lxk)
{
    int l = blockIdx.x;
    int lane = threadIdx.x;

    float acc[DIM];
    #pragma unroll
    for (int d = 0; d < DIM; d++) acc[d] = 0.0f;

    for (int j = lane; j < MAX_PL; j += 64) {
        const int* e = p2l + (size_t)(l * MAX_PL + j) * 2;
        int pi = e[0];
        int si = e[1];
        const float* g = seq + ((size_t)si * N_PATHS + pi) * DIM;
        #pragma unroll
        for (int d = 0; d < DIM; d++) acc[d] += g[d];
    }
    #pragma unroll
    for (int off = 32; off > 0; off >>= 1) {
        #pragma unroll
        for (int d = 0; d < DIM; d++) acc[d] += __shfl_xor(acc[d], off);
    }

    // old link state (uniform address per block)
    float h[DIM];
    #pragma unroll
    for (int d = 0; d < DIM; d++) h[d] = ls[(size_t)l * DIM + d];

    // lanes 0..47 each compute one column of mx, mi
    int j = (lane < 48) ? lane : 0;
    float mx = lb[j];
    float mi = lb[48 + j];
    #pragma unroll
    for (int k = 0; k < DIM; k++) {
        mx = fmaf(acc[k], lk[k * 48 + j], mx);
        mi = fmaf(h[k],  lrk[k * 48 + j], mi);
    }

    int d = lane & 15;
    float xz = __shfl(mx, d),      rz = __shfl(mi, d);
    float xr = __shfl(mx, d + 16), rr = __shfl(mi, d + 16);
    float xh = __shfl(mx, d + 32), rh = __shfl(mi, d + 32);
    float z  = sigmoidf_(xz + rz);
    float r  = sigmoidf_(xr + rr);
    float hh = tanhf(xh + r * rh);
    float hn = z * h[d] + (1.0f - z) * hh;

    if (lane < DIM) ls[(size_t)l * DIM + lane] = hn;

    // broadcast new h to all lanes, then compute lxk column per lane
    float hf[DIM];
    #pragma unroll
    for (int k = 0; k < DIM; k++) hf[k] = __shfl(hn, k);
    if (lane < 48) {
        float a = pb[lane];
        #pragma unroll
        for (int k = 0; k < DIM; k++) a = fmaf(hf[k], pk[k * 48 + lane], a);
        lxk[(size_t)l * 48 + lane] = a;
    }
}

// ---------------- readout ----------------
__global__ __launch_bounds__(256) void k_readout(
    const float* __restrict__ seq, const int* __restrict__ l2p,
    const float* __restrict__ cap,
    const float* __restrict__ w1, const float* __restrict__ b1,
    const float* __restrict__ w2, const float* __restrict__ b2,
    const float* __restrict__ w3, const float* __restrict__ b3,
    float* __restrict__ out)
{
    int p = blockIdx.x * blockDim.x + threadIdx.x;
    if (p >= N_PATHS) return;
    float delay = 0.0f;
    for (int t = 1; t <= PATH_LEN; t++) {
        const float* hp = seq + ((size_t)t * N_PATHS + p) * DIM;
        float h[DIM];
        #pragma unroll
        for (int d = 0; d < DIM; d++) h[d] = hp[d];

        float h1[8];
        #pragma unroll
        for (int j = 0; j < 8; j++) {
            float a = b1[j];
            #pragma unroll
            for (int k = 0; k < DIM; k++) a = fmaf(h[k], w1[k * 8 + j], a);
            h1[j] = fmaxf(a, 0.0f);
        }
        float h2[4];
        #pragma unroll
        for (int j = 0; j < 4; j++) {
            float a = b2[j];
            #pragma unroll
            for (int k = 0; k < 8; k++) a = fmaf(h1[k], w2[k * 4 + j], a);
            h2[j] = fmaxf(a, 0.0f);
        }
        float o = b3[0];
        #pragma unroll
        for (int k = 0; k < 4; k++) o = fmaf(h2[k], w3[k], o);
        o = softplusf_(o);

        float c = cap[l2p[(size_t)p * PATH_LEN + (t - 1)]];
        delay += o / c;
    }
    out[p] = delay;
}

extern "C" void kernel_launch(void* const* d_in, const int* in_sizes, int n_in,
                              void* d_out, int out_size, void* d_ws, size_t ws_size,
                              hipStream_t stream)
{
    const float* flow_traffic = (const float*)d_in[0];
    const float* flow_packets = (const float*)d_in[1];
    const float* flow_pktsize = (const float*)d_in[2];
    const float* flow_type    = (const float*)d_in[3];
    const float* link_cap     = (const float*)d_in[4];
    const int*   l2p          = (const int*)d_in[5];
    const int*   p2l          = (const int*)d_in[6];
    const float* fe_w1 = (const float*)d_in[7];
    const float* fe_b1 = (const float*)d_in[8];
    const float* fe_w2 = (const float*)d_in[9];
    const float* fe_b2 = (const float*)d_in[10];
    const float* le_w1 = (const float*)d_in[11];
    const float* le_b1 = (const float*)d_in[12];
    const float* le_w2 = (const float*)d_in[13];
    const float* le_b2 = (const float*)d_in[14];
    const float* pgru_k  = (const float*)d_in[15];
    const float* pgru_rk = (const float*)d_in[16];
    const float* pgru_b  = (const float*)d_in[17];
    const float* lgru_k  = (const float*)d_in[18];
    const float* lgru_rk = (const float*)d_in[19];
    const float* lgru_b  = (const float*)d_in[20];
    const float* ro_w1 = (const float*)d_in[21];
    const float* ro_b1 = (const float*)d_in[22];
    const float* ro_w2 = (const float*)d_in[23];
    const float* ro_b2 = (const float*)d_in[24];
    const float* ro_w3 = (const float*)d_in[25];
    const float* ro_b3 = (const float*)d_in[26];
    float* out = (float*)d_out;

    char* ws = (char*)d_ws;
    float* seq = (float*)ws;
    float* ls  = (float*)(ws + SEQ_BYTES);
    float* lxk = (float*)(ws + SEQ_BYTES + LS_BYTES);

    k_init_links<<<N_LINKS, 64, 0, stream>>>(flow_traffic, link_cap, p2l,
        le_w1, le_b1, le_w2, le_b2, pgru_k, pgru_b, ls, lxk);
    k_init_paths<<<(N_PATHS + 255) / 256, 256, 0, stream>>>(flow_traffic,
        flow_packets, flow_pktsize, flow_type, fe_w1, fe_b1, fe_w2, fe_b2, seq);

    for (int it = 0; it < ITERS; ++it) {
        k_paths<<<(N_PATHS + 255) / 256, 256, 0, stream>>>(l2p, lxk,
            pgru_rk, pgru_b, seq);
        k_links<<<N_LINKS, 64, 0, stream>>>(p2l, seq, lgru_k, lgru_rk, lgru_b,
            pgru_k, pgru_b, ls, lxk);
    }

    k_readout<<<(N_PATHS + 255) / 256, 256, 0, stream>>>(seq, l2p, link_cap,
        ro_w1, ro_b1, ro_w2, ro_b2, ro_w3, ro_b3, out);
}

// Round 2
// 879.971 us; speedup vs baseline: 8.2952x; 8.2952x over previous
//
#include <hip/hip_runtime.h>
#include <hip/hip_bf16.h>
#include <math.h>

#define N_PATHS  200000
#define PATH_LEN 8
#define N_LINKS  20000
#define MAX_PL   100
#define DIM      16
#define ITERS    8

// workspace layout (bytes):
//   seq : float[9][N_PATHS][DIM]   = 115,200,000   (path_state_sequence; slot 8 = current path_state)
//   ls  : float[N_LINKS][DIM]      =   1,280,000   (link_state)
//   lxk : float[N_LINKS][48]       =   3,840,000   (link_state @ pgru_k + pgru_b[0])
#define SEQ_BYTES 115200000ull
#define LS_BYTES  1280000ull

__device__ __forceinline__ float fast_sigmoid(float x) {
    // 1 / (1 + e^-x); v_exp + v_rcp
    return __builtin_amdgcn_rcpf(1.0f + __expf(-x));
}
__device__ __forceinline__ float fast_tanh(float x) {
    float ax = fabsf(x);
    float t  = __expf(-2.0f * ax);
    float r  = (1.0f - t) * __builtin_amdgcn_rcpf(1.0f + t);
    return copysignf(r, x);
}
__device__ __forceinline__ float softplusf_(float x) {
    return fmaxf(x, 0.0f) + log1pf(expf(-fabsf(x)));
}

// broadcast from lane ((lane & 0x10) | SRC) within each 32-lane half => broadcast
// within each aligned 16-lane group. offset = (or<<5) | and, and=0x10 keeps bit4.
#define BCASTF(v, SRC) __int_as_float(__builtin_amdgcn_ds_swizzle(__float_as_int(v), (((SRC) << 5) | 0x10)))
#define BCASTI(v, SRC) __builtin_amdgcn_ds_swizzle((v), (((SRC) << 5) | 0x10))

// ---------------- init: link load -> link_state -> lxk ----------------
__global__ __launch_bounds__(64) void k_init_links(
    const float* __restrict__ traffic, const float* __restrict__ cap,
    const int* __restrict__ p2l,
    const float* __restrict__ le_w1, const float* __restrict__ le_b1,
    const float* __restrict__ le_w2, const float* __restrict__ le_b2,
    const float* __restrict__ pk, const float* __restrict__ pb,
    float* __restrict__ ls, float* __restrict__ lxk)
{
    int l = blockIdx.x;
    int lane = threadIdx.x;
    float s = 0.0f;
    for (int j = lane; j < MAX_PL; j += 64) {
        int p = p2l[(size_t)(l * MAX_PL + j) * 2 + 0];
        s += traffic[p];
    }
    #pragma unroll
    for (int off = 32; off > 0; off >>= 1) s += __shfl_xor(s, off);

    float c = cap[l];
    float f0 = c * 0.1f;
    float f1 = s / (c * 1e9f);

    float h1[DIM];
    #pragma unroll
    for (int d = 0; d < DIM; d++)
        h1[d] = fmaxf(f0 * le_w1[d] + f1 * le_w1[DIM + d] + le_b1[d], 0.0f);

    float h2[DIM];
    #pragma unroll
    for (int d = 0; d < DIM; d++) {
        float a = le_b2[d];
        #pragma unroll
        for (int k = 0; k < DIM; k++) a = fmaf(h1[k], le_w2[k * DIM + d], a);
        h2[d] = fmaxf(a, 0.0f);
    }
    if (lane < DIM) ls[(size_t)l * DIM + lane] = h2[lane];
    if (lane < 48) {
        float a = pb[lane];
        #pragma unroll
        for (int k = 0; k < DIM; k++) a = fmaf(h2[k], pk[k * 48 + lane], a);
        lxk[(size_t)l * 48 + lane] = a;
    }
}

// ---------------- init: path_state -> seq[8] ----------------
__global__ __launch_bounds__(256) void k_init_paths(
    const float* __restrict__ traffic, const float* __restrict__ packets,
    const float* __restrict__ pktsize, const float* __restrict__ ftype,
    const float* __restrict__ fe_w1, const float* __restrict__ fe_b1,
    const float* __restrict__ fe_w2, const float* __restrict__ fe_b2,
    float* __restrict__ seq)
{
    int p = blockIdx.x * blockDim.x + threadIdx.x;
    if (p >= N_PATHS) return;
    float f[5];
    f[0] = traffic[p] * 0.0001f;
    f[1] = packets[p] * 0.01f;
    f[2] = pktsize[p] * 0.001f;
    f[3] = ftype[p * 2 + 0];
    f[4] = ftype[p * 2 + 1];

    float h1[DIM];
    #pragma unroll
    for (int d = 0; d < DIM; d++) {
        float a = fe_b1[d];
        #pragma unroll
        for (int k = 0; k < 5; k++) a = fmaf(f[k], fe_w1[k * DIM + d], a);
        h1[d] = fmaxf(a, 0.0f);
    }
    float* out = seq + ((size_t)8 * N_PATHS + p) * DIM;
    #pragma unroll
    for (int d = 0; d < DIM; d++) {
        float a = fe_b2[d];
        #pragma unroll
        for (int k = 0; k < DIM; k++) a = fmaf(h1[k], fe_w2[k * DIM + d], a);
        out[d] = fmaxf(a, 0.0f);
    }
}

// ---------------- per-iteration: path GRU, 16 lanes per path ----------------
// lane d of each 16-lane group owns h[d] and gate columns {d, d+16, d+32}.
// Recurrent weights held in 48 registers per lane. h broadcast via ds_swizzle.
#define KSTEP(k) { float hk = BCASTF(h, k); \
    mz = fmaf(hk, rkz[k], mz); mr = fmaf(hk, rkr[k], mr); mh = fmaf(hk, rkh[k], mh); }

#define K16 KSTEP(0) KSTEP(1) KSTEP(2) KSTEP(3) KSTEP(4) KSTEP(5) KSTEP(6) KSTEP(7) \
            KSTEP(8) KSTEP(9) KSTEP(10) KSTEP(11) KSTEP(12) KSTEP(13) KSTEP(14) KSTEP(15)

#define STEP(t) { \
    int li = BCASTI(myidx, t); \
    const float* xp = lxk + (size_t)li * 48 + d; \
    float x0 = xp[0], x1 = xp[16], x2 = xp[32]; \
    float mz = bz, mr = br, mh = bh; \
    K16 \
    float z  = fast_sigmoid(x0 + mz); \
    float r  = fast_sigmoid(x1 + mr); \
    float hh = fast_tanh(x2 + r * mh); \
    h = z * h + (1.0f - z) * hh; \
    seq[((size_t)((t) + 1) * N_PATHS + p) * DIM + d] = h; \
}

__global__ __launch_bounds__(256) void k_paths(
    const int* __restrict__ l2p, const float* __restrict__ lxk,
    const float* __restrict__ rk, const float* __restrict__ b,
    float* __restrict__ seq)
{
    int tid = blockIdx.x * 256 + threadIdx.x;
    int p = tid >> 4;                 // grid is exact: 200000*16/256 = 12500 blocks
    int d = threadIdx.x & 15;

    float rkz[16], rkr[16], rkh[16];
    #pragma unroll
    for (int k = 0; k < 16; k++) {
        rkz[k] = rk[k * 48 + d];
        rkr[k] = rk[k * 48 + 16 + d];
        rkh[k] = rk[k * 48 + 32 + d];
    }
    float bz = b[48 + d], br = b[48 + 16 + d], bh = b[48 + 32 + d];

    int myidx = l2p[(size_t)p * PATH_LEN + (d & 7)];

    float h = seq[((size_t)8 * N_PATHS + p) * DIM + d];
    seq[(size_t)p * DIM + d] = h;     // entry 0 = prev

    STEP(0) STEP(1) STEP(2) STEP(3) STEP(4) STEP(5) STEP(6) STEP(7)
}

// ---------------- per-iteration: link aggregate + link GRU + lxk ----------------
__global__ __launch_bounds__(64) void k_links(
    const int* __restrict__ p2l, const float* __restrict__ seq,
    const float* __restrict__ lk, const float* __restrict__ lrk,
    const float* __restrict__ lb,
    const float* __restrict__ pk, const float* __restrict__ pb,
    float* ls, float* __restrict__ lxk)
{
    int l = blockIdx.x;
    int lane = threadIdx.x;

    float acc[DIM];
    #pragma unroll
    for (int d = 0; d < DIM; d++) acc[d] = 0.0f;

    for (int j = lane; j < MAX_PL; j += 64) {
        const int* e = p2l + (size_t)(l * MAX_PL + j) * 2;
        int pi = e[0];
        int si = e[1];
        const float* g = seq + ((size_t)si * N_PATHS + pi) * DIM;
        #pragma unroll
        for (int d = 0; d < DIM; d++) acc[d] += g[d];
    }
    #pragma unroll
    for (int off = 32; off > 0; off >>= 1) {
        #pragma unroll
        for (int d = 0; d < DIM; d++) acc[d] += __shfl_xor(acc[d], off);
    }

    float h[DIM];
    #pragma unroll
    for (int d = 0; d < DIM; d++) h[d] = ls[(size_t)l * DIM + d];

    int j = (lane < 48) ? lane : 0;
    float mx = lb[j];
    float mi = lb[48 + j];
    #pragma unroll
    for (int k = 0; k < DIM; k++) {
        mx = fmaf(acc[k], lk[k * 48 + j], mx);
        mi = fmaf(h[k],  lrk[k * 48 + j], mi);
    }

    int d = lane & 15;
    float xz = __shfl(mx, d),      rz = __shfl(mi, d);
    float xr = __shfl(mx, d + 16), rr = __shfl(mi, d + 16);
    float xh = __shfl(mx, d + 32), rh = __shfl(mi, d + 32);
    float z  = fast_sigmoid(xz + rz);
    float r  = fast_sigmoid(xr + rr);
    float hh = fast_tanh(xh + r * rh);
    float hn = z * h[d] + (1.0f - z) * hh;

    if (lane < DIM) ls[(size_t)l * DIM + lane] = hn;

    float hf[DIM];
    #pragma unroll
    for (int k = 0; k < DIM; k++) hf[k] = __shfl(hn, k);
    if (lane < 48) {
        float a = pb[lane];
        #pragma unroll
        for (int k = 0; k < DIM; k++) a = fmaf(hf[k], pk[k * 48 + lane], a);
        lxk[(size_t)l * 48 + lane] = a;
    }
}

// ---------------- readout ----------------
__global__ __launch_bounds__(256) void k_readout(
    const float* __restrict__ seq, const int* __restrict__ l2p,
    const float* __restrict__ cap,
    const float* __restrict__ w1, const float* __restrict__ b1,
    const float* __restrict__ w2, const float* __restrict__ b2,
    const float* __restrict__ w3, const float* __restrict__ b3,
    float* __restrict__ out)
{
    int p = blockIdx.x * blockDim.x + threadIdx.x;
    if (p >= N_PATHS) return;
    float delay = 0.0f;
    for (int t = 1; t <= PATH_LEN; t++) {
        const float* hp = seq + ((size_t)t * N_PATHS + p) * DIM;
        float h[DIM];
        #pragma unroll
        for (int d = 0; d < DIM; d++) h[d] = hp[d];

        float h1[8];
        #pragma unroll
        for (int j = 0; j < 8; j++) {
            float a = b1[j];
            #pragma unroll
            for (int k = 0; k < DIM; k++) a = fmaf(h[k], w1[k * 8 + j], a);
            h1[j] = fmaxf(a, 0.0f);
        }
        float h2[4];
        #pragma unroll
        for (int j = 0; j < 4; j++) {
            float a = b2[j];
            #pragma unroll
            for (int k = 0; k < 8; k++) a = fmaf(h1[k], w2[k * 4 + j], a);
            h2[j] = fmaxf(a, 0.0f);
        }
        float o = b3[0];
        #pragma unroll
        for (int k = 0; k < 4; k++) o = fmaf(h2[k], w3[k], o);
        o = softplusf_(o);

        float c = cap[l2p[(size_t)p * PATH_LEN + (t - 1)]];
        delay += o / c;
    }
    out[p] = delay;
}

extern "C" void kernel_launch(void* const* d_in, const int* in_sizes, int n_in,
                              void* d_out, int out_size, void* d_ws, size_t ws_size,
                              hipStream_t stream)
{
    const float* flow_traffic = (const float*)d_in[0];
    const float* flow_packets = (const float*)d_in[1];
    const float* flow_pktsize = (const float*)d_in[2];
    const float* flow_type    = (const float*)d_in[3];
    const float* link_cap     = (const float*)d_in[4];
    const int*   l2p          = (const int*)d_in[5];
    const int*   p2l          = (const int*)d_in[6];
    const float* fe_w1 = (const float*)d_in[7];
    const float* fe_b1 = (const float*)d_in[8];
    const float* fe_w2 = (const float*)d_in[9];
    const float* fe_b2 = (const float*)d_in[10];
    const float* le_w1 = (const float*)d_in[11];
    const float* le_b1 = (const float*)d_in[12];
    const float* le_w2 = (const float*)d_in[13];
    const float* le_b2 = (const float*)d_in[14];
    const float* pgru_k  = (const float*)d_in[15];
    const float* pgru_rk = (const float*)d_in[16];
    const float* pgru_b  = (const float*)d_in[17];
    const float* lgru_k  = (const float*)d_in[18];
    const float* lgru_rk = (const float*)d_in[19];
    const float* lgru_b  = (const float*)d_in[20];
    const float* ro_w1 = (const float*)d_in[21];
    const float* ro_b1 = (const float*)d_in[22];
    const float* ro_w2 = (const float*)d_in[23];
    const float* ro_b2 = (const float*)d_in[24];
    const float* ro_w3 = (const float*)d_in[25];
    const float* ro_b3 = (const float*)d_in[26];
    float* out = (float*)d_out;

    char* ws = (char*)d_ws;
    float* seq = (float*)ws;
    float* ls  = (float*)(ws + SEQ_BYTES);
    float* lxk = (float*)(ws + SEQ_BYTES + LS_BYTES);

    k_init_links<<<N_LINKS, 64, 0, stream>>>(flow_traffic, link_cap, p2l,
        le_w1, le_b1, le_w2, le_b2, pgru_k, pgru_b, ls, lxk);
    k_init_paths<<<(N_PATHS + 255) / 256, 256, 0, stream>>>(flow_traffic,
        flow_packets, flow_pktsize, flow_type, fe_w1, fe_b1, fe_w2, fe_b2, seq);

    for (int it = 0; it < ITERS; ++it) {
        k_paths<<<(N_PATHS * 16) / 256, 256, 0, stream>>>(l2p, lxk,
            pgru_rk, pgru_b, seq);
        k_links<<<N_LINKS, 64, 0, stream>>>(p2l, seq, lgru_k, lgru_rk, lgru_b,
            pgru_k, pgru_b, ls, lxk);
    }

    k_readout<<<(N_PATHS + 255) / 256, 256, 0, stream>>>(seq, l2p, link_cap,
        ro_w1, ro_b1, ro_w2, ro_b2, ro_w3, ro_b3, out);
}

// Round 3
// 677.891 us; speedup vs baseline: 10.7680x; 1.2981x over previous
//
#include <hip/hip_runtime.h>
#include <hip/hip_bf16.h>
#include <math.h>

#define N_PATHS  200000
#define PATH_LEN 8
#define N_LINKS  20000
#define MAX_PL   100
#define DIM      16
#define ITERS    8

typedef __attribute__((ext_vector_type(8))) short bf16x8;
typedef __attribute__((ext_vector_type(4))) float f32x4;

// ws layout (bytes):
//   seq  : ushort[9][N_PATHS][16]  = 57,600,000  (bf16 path_state_sequence; slot 8 = current path_state)
//   ls   : float [N_LINKS][16]     =  1,280,000  (link_state, fp32)
//   lxk  : ushort[N_LINKS][48]     =  1,920,000  (bf16: link_state @ pgru_k + pgru_b[0])
//   p2lp : uint  [N_LINKS*MAX_PL]  =  8,000,000  (packed (s<<18)|p)
#define SEQ_BYTES 57600000ull
#define LS_BYTES  1280000ull
#define LXK_BYTES 1920000ull

__device__ __forceinline__ float fast_sigmoid(float x) {
    return __builtin_amdgcn_rcpf(1.0f + __expf(-x));
}
__device__ __forceinline__ float fast_tanh(float x) {
    float ax = fabsf(x);
    float t  = __expf(-2.0f * ax);
    float r  = (1.0f - t) * __builtin_amdgcn_rcpf(1.0f + t);
    return copysignf(r, x);
}
__device__ __forceinline__ float softplusf_(float x) {
    return fmaxf(x, 0.0f) + log1pf(expf(-fabsf(x)));
}
__device__ __forceinline__ float bflo(unsigned int u) {
    union { unsigned int i; float f; } c; c.i = u << 16; return c.f;
}
__device__ __forceinline__ float bfhi(unsigned int u) {
    union { unsigned int i; float f; } c; c.i = u & 0xffff0000u; return c.f;
}
__device__ __forceinline__ unsigned int pk_bf16(float lo, float hi) {
    unsigned int r;
    asm("v_cvt_pk_bf16_f32 %0, %1, %2" : "=v"(r) : "v"(lo), "v"(hi));
    return r;
}

union U8 { unsigned int u[4]; bf16x8 v; };

// ---------------- pack p2l ----------------
__global__ __launch_bounds__(256) void k_pack(const int* __restrict__ p2l,
                                              unsigned int* __restrict__ out)
{
    int i = blockIdx.x * 256 + threadIdx.x;
    if (i < N_LINKS * MAX_PL) {
        unsigned int pi = (unsigned int)p2l[2 * i];
        unsigned int si = (unsigned int)p2l[2 * i + 1];
        out[i] = (si << 18) | pi;
    }
}

// ---------------- init: link load -> link_state -> lxk ----------------
__global__ __launch_bounds__(64) void k_init_links(
    const float* __restrict__ traffic, const float* __restrict__ cap,
    const int* __restrict__ p2l,
    const float* __restrict__ le_w1, const float* __restrict__ le_b1,
    const float* __restrict__ le_w2, const float* __restrict__ le_b2,
    const float* __restrict__ pk, const float* __restrict__ pb,
    float* __restrict__ ls, unsigned short* __restrict__ lxk)
{
    int l = blockIdx.x;
    int lane = threadIdx.x;
    float s = 0.0f;
    for (int j = lane; j < MAX_PL; j += 64) {
        int p = p2l[(size_t)(l * MAX_PL + j) * 2 + 0];
        s += traffic[p];
    }
    #pragma unroll
    for (int off = 32; off > 0; off >>= 1) s += __shfl_xor(s, off);

    float c = cap[l];
    float f0 = c * 0.1f;
    float f1 = s / (c * 1e9f);

    float h1[DIM];
    #pragma unroll
    for (int d = 0; d < DIM; d++)
        h1[d] = fmaxf(f0 * le_w1[d] + f1 * le_w1[DIM + d] + le_b1[d], 0.0f);

    float h2[DIM];
    #pragma unroll
    for (int d = 0; d < DIM; d++) {
        float a = le_b2[d];
        #pragma unroll
        for (int k = 0; k < DIM; k++) a = fmaf(h1[k], le_w2[k * DIM + d], a);
        h2[d] = fmaxf(a, 0.0f);
    }
    if (lane < DIM) ls[(size_t)l * DIM + lane] = h2[lane];
    if (lane < 48) {
        float a = pb[lane];
        #pragma unroll
        for (int k = 0; k < DIM; k++) a = fmaf(h2[k], pk[k * 48 + lane], a);
        lxk[(size_t)l * 48 + lane] = (unsigned short)(pk_bf16(a, a) & 0xffffu);
    }
}

// ---------------- init: path_state -> seq[8] (bf16) ----------------
__global__ __launch_bounds__(256) void k_init_paths(
    const float* __restrict__ traffic, const float* __restrict__ packets,
    const float* __restrict__ pktsize, const float* __restrict__ ftype,
    const float* __restrict__ fe_w1, const float* __restrict__ fe_b1,
    const float* __restrict__ fe_w2, const float* __restrict__ fe_b2,
    unsigned short* __restrict__ seq)
{
    int p = blockIdx.x * blockDim.x + threadIdx.x;
    if (p >= N_PATHS) return;
    float f[5];
    f[0] = traffic[p] * 0.0001f;
    f[1] = packets[p] * 0.01f;
    f[2] = pktsize[p] * 0.001f;
    f[3] = ftype[p * 2 + 0];
    f[4] = ftype[p * 2 + 1];

    float h1[DIM];
    #pragma unroll
    for (int d = 0; d < DIM; d++) {
        float a = fe_b1[d];
        #pragma unroll
        for (int k = 0; k < 5; k++) a = fmaf(f[k], fe_w1[k * DIM + d], a);
        h1[d] = fmaxf(a, 0.0f);
    }
    float h2[DIM];
    #pragma unroll
    for (int d = 0; d < DIM; d++) {
        float a = fe_b2[d];
        #pragma unroll
        for (int k = 0; k < DIM; k++) a = fmaf(h1[k], fe_w2[k * DIM + d], a);
        h2[d] = fmaxf(a, 0.0f);
    }
    unsigned int pkd[8];
    #pragma unroll
    for (int q = 0; q < 8; q++) pkd[q] = pk_bf16(h2[2 * q], h2[2 * q + 1]);
    uint4* out = (uint4*)(seq + ((size_t)8 * N_PATHS + p) * DIM);
    out[0] = make_uint4(pkd[0], pkd[1], pkd[2], pkd[3]);
    out[1] = make_uint4(pkd[4], pkd[5], pkd[6], pkd[7]);
}

// ---------------- per-iteration: path GRU via MFMA, 16 paths/wave ----------------
// D/C layout (16x16x32_bf16, verified m89): col=lane&15, row=(lane>>4)*4+reg.
// A/B assumed split-K layout: k = 4*(lane>>4) + (i&3) + 16*(i>>2); we duplicate
// weights*0.5 in both halves and h in both B halves so either half-order works.
__global__ __launch_bounds__(256) void k_paths(
    const int* __restrict__ l2p, const unsigned short* __restrict__ lxk,
    const float* __restrict__ rk, const float* __restrict__ b,
    unsigned short* __restrict__ seq)
{
    int l = threadIdx.x & 63;
    int wave = (blockIdx.x * 256 + threadIdx.x) >> 6;   // 0..12499
    int pr = l & 15;            // path-in-wave / D column / A row (gate col)
    int g  = l >> 4;            // 0..3
    int kq = g * 4;             // k/dim/row quad base
    int p  = wave * 16 + pr;

    // A-frags (constant): A[m=pr][k] = 0.5*rk[k&15][gate*16+pr], halves duplicated
    U8 Az, Ar, Ah;
    {
        #pragma unroll
        for (int i = 0; i < 2; i++) {
            float wz0 = rk[(kq + 2 * i) * 48 + pr] * 0.5f;
            float wz1 = rk[(kq + 2 * i + 1) * 48 + pr] * 0.5f;
            float wr0 = rk[(kq + 2 * i) * 48 + 16 + pr] * 0.5f;
            float wr1 = rk[(kq + 2 * i + 1) * 48 + 16 + pr] * 0.5f;
            float wh0 = rk[(kq + 2 * i) * 48 + 32 + pr] * 0.5f;
            float wh1 = rk[(kq + 2 * i + 1) * 48 + 32 + pr] * 0.5f;
            Az.u[i] = pk_bf16(wz0, wz1); Az.u[i + 2] = Az.u[i];
            Ar.u[i] = pk_bf16(wr0, wr1); Ar.u[i + 2] = Ar.u[i];
            Ah.u[i] = pk_bf16(wh0, wh1); Ah.u[i + 2] = Ah.u[i];
        }
    }
    // C-init = recurrent biases b[1][gate*16 + row], row = kq + reg
    f32x4 Cz, Cr, Ch;
    #pragma unroll
    for (int r = 0; r < 4; r++) {
        Cz[r] = b[48 + kq + r];
        Cr[r] = b[48 + 16 + kq + r];
        Ch[r] = b[48 + 32 + kq + r];
    }

    // l2p preload: lane holds steps {2g, 2g+1} for path p
    int2 idx2 = *(const int2*)(l2p + (size_t)p * PATH_LEN + 2 * g);

    // h from seq slot 8; copy to slot 0
    float h0, h1, h2, h3;
    U8 B;
    {
        uint2 hp = *(const uint2*)(seq + ((size_t)8 * N_PATHS + p) * DIM + kq);
        *(uint2*)(seq + (size_t)p * DIM + kq) = hp;
        h0 = bflo(hp.x); h1 = bfhi(hp.x); h2 = bflo(hp.y); h3 = bfhi(hp.y);
        B.u[0] = hp.x; B.u[1] = hp.y; B.u[2] = hp.x; B.u[3] = hp.y;
    }

    #pragma unroll
    for (int t = 0; t < PATH_LEN; t++) {
        int li = __shfl((t & 1) ? idx2.y : idx2.x, pr + 16 * (t >> 1));
        const unsigned short* xp = lxk + (size_t)li * 48 + kq;
        uint2 uz = *(const uint2*)(xp);          // 4 bf16: mx_z[kq..kq+3]
        uint2 ur = *(const uint2*)(xp + 16);
        uint2 uh = *(const uint2*)(xp + 32);

        f32x4 az = __builtin_amdgcn_mfma_f32_16x16x32_bf16(Az.v, B.v, Cz, 0, 0, 0);
        f32x4 ar = __builtin_amdgcn_mfma_f32_16x16x32_bf16(Ar.v, B.v, Cr, 0, 0, 0);
        f32x4 ah = __builtin_amdgcn_mfma_f32_16x16x32_bf16(Ah.v, B.v, Ch, 0, 0, 0);

        float mz0 = bflo(uz.x), mz1 = bfhi(uz.x), mz2 = bflo(uz.y), mz3 = bfhi(uz.y);
        float mr0 = bflo(ur.x), mr1 = bfhi(ur.x), mr2 = bflo(ur.y), mr3 = bfhi(ur.y);
        float mh0 = bflo(uh.x), mh1 = bfhi(uh.x), mh2 = bflo(uh.y), mh3 = bfhi(uh.y);

        float z0 = fast_sigmoid(mz0 + az[0]), z1 = fast_sigmoid(mz1 + az[1]);
        float z2 = fast_sigmoid(mz2 + az[2]), z3 = fast_sigmoid(mz3 + az[3]);
        float r0 = fast_sigmoid(mr0 + ar[0]), r1 = fast_sigmoid(mr1 + ar[1]);
        float r2 = fast_sigmoid(mr2 + ar[2]), r3 = fast_sigmoid(mr3 + ar[3]);
        float q0 = fast_tanh(mh0 + r0 * ah[0]), q1 = fast_tanh(mh1 + r1 * ah[1]);
        float q2 = fast_tanh(mh2 + r2 * ah[2]), q3 = fast_tanh(mh3 + r3 * ah[3]);

        h0 = z0 * h0 + (1.0f - z0) * q0;
        h1 = z1 * h1 + (1.0f - z1) * q1;
        h2 = z2 * h2 + (1.0f - z2) * q2;
        h3 = z3 * h3 + (1.0f - z3) * q3;

        unsigned int p01 = pk_bf16(h0, h1);
        unsigned int p23 = pk_bf16(h2, h3);
        *(uint2*)(seq + ((size_t)(t + 1) * N_PATHS + p) * DIM + kq) = make_uint2(p01, p23);
        B.u[0] = p01; B.u[1] = p23; B.u[2] = p01; B.u[3] = p23;
    }
}

// ---------------- per-iteration: link aggregate + link GRU + lxk ----------------
__global__ __launch_bounds__(64) void k_links(
    const unsigned int* __restrict__ p2lp, const unsigned short* __restrict__ seq,
    const float* __restrict__ lk, const float* __restrict__ lrk,
    const float* __restrict__ lb,
    const float* __restrict__ pk, const float* __restrict__ pb,
    float* ls, unsigned short* __restrict__ lxk)
{
    int l = blockIdx.x;
    int lane = threadIdx.x;

    float acc[DIM];
    #pragma unroll
    for (int d = 0; d < DIM; d++) acc[d] = 0.0f;

    for (int j = lane; j < MAX_PL; j += 64) {
        unsigned int e = p2lp[(size_t)l * MAX_PL + j];
        unsigned int pi = e & 0x3FFFFu;
        unsigned int si = e >> 18;
        const uint4* gp = (const uint4*)(seq + ((size_t)si * N_PATHS + pi) * DIM);
        uint4 a = gp[0], c = gp[1];
        acc[0]  += bflo(a.x); acc[1]  += bfhi(a.x);
        acc[2]  += bflo(a.y); acc[3]  += bfhi(a.y);
        acc[4]  += bflo(a.z); acc[5]  += bfhi(a.z);
        acc[6]  += bflo(a.w); acc[7]  += bfhi(a.w);
        acc[8]  += bflo(c.x); acc[9]  += bfhi(c.x);
        acc[10] += bflo(c.y); acc[11] += bfhi(c.y);
        acc[12] += bflo(c.z); acc[13] += bfhi(c.z);
        acc[14] += bflo(c.w); acc[15] += bfhi(c.w);
    }
    #pragma unroll
    for (int off = 32; off > 0; off >>= 1) {
        #pragma unroll
        for (int d = 0; d < DIM; d++) acc[d] += __shfl_xor(acc[d], off);
    }

    float h[DIM];
    #pragma unroll
    for (int d = 0; d < DIM; d++) h[d] = ls[(size_t)l * DIM + d];

    int j = (lane < 48) ? lane : 0;
    float mx = lb[j];
    float mi = lb[48 + j];
    #pragma unroll
    for (int k = 0; k < DIM; k++) {
        mx = fmaf(acc[k], lk[k * 48 + j], mx);
        mi = fmaf(h[k],  lrk[k * 48 + j], mi);
    }

    int d = lane & 15;
    float xz = __shfl(mx, d),      rz = __shfl(mi, d);
    float xr = __shfl(mx, d + 16), rr = __shfl(mi, d + 16);
    float xh = __shfl(mx, d + 32), rh = __shfl(mi, d + 32);
    float z  = fast_sigmoid(xz + rz);
    float r  = fast_sigmoid(xr + rr);
    float hh = fast_tanh(xh + r * rh);
    float hn = z * h[d] + (1.0f - z) * hh;

    if (lane < DIM) ls[(size_t)l * DIM + lane] = hn;

    float hf[DIM];
    #pragma unroll
    for (int k = 0; k < DIM; k++) hf[k] = __shfl(hn, k);
    if (lane < 48) {
        float a = pb[lane];
        #pragma unroll
        for (int k = 0; k < DIM; k++) a = fmaf(hf[k], pk[k * 48 + lane], a);
        lxk[(size_t)l * 48 + lane] = (unsigned short)(pk_bf16(a, a) & 0xffffu);
    }
}

// ---------------- readout ----------------
__global__ __launch_bounds__(256) void k_readout(
    const unsigned short* __restrict__ seq, const int* __restrict__ l2p,
    const float* __restrict__ cap,
    const float* __restrict__ w1, const float* __restrict__ b1,
    const float* __restrict__ w2, const float* __restrict__ b2,
    const float* __restrict__ w3, const float* __restrict__ b3,
    float* __restrict__ out)
{
    int p = blockIdx.x * blockDim.x + threadIdx.x;
    if (p >= N_PATHS) return;
    float delay = 0.0f;
    for (int t = 1; t <= PATH_LEN; t++) {
        const uint4* gp = (const uint4*)(seq + ((size_t)t * N_PATHS + p) * DIM);
        uint4 a = gp[0], c = gp[1];
        float h[DIM];
        h[0]  = bflo(a.x); h[1]  = bfhi(a.x); h[2]  = bflo(a.y); h[3]  = bfhi(a.y);
        h[4]  = bflo(a.z); h[5]  = bfhi(a.z); h[6]  = bflo(a.w); h[7]  = bfhi(a.w);
        h[8]  = bflo(c.x); h[9]  = bfhi(c.x); h[10] = bflo(c.y); h[11] = bfhi(c.y);
        h[12] = bflo(c.z); h[13] = bfhi(c.z); h[14] = bflo(c.w); h[15] = bfhi(c.w);

        float h1[8];
        #pragma unroll
        for (int jj = 0; jj < 8; jj++) {
            float a1 = b1[jj];
            #pragma unroll
            for (int k = 0; k < DIM; k++) a1 = fmaf(h[k], w1[k * 8 + jj], a1);
            h1[jj] = fmaxf(a1, 0.0f);
        }
        float h2[4];
        #pragma unroll
        for (int jj = 0; jj < 4; jj++) {
            float a2 = b2[jj];
            #pragma unroll
            for (int k = 0; k < 8; k++) a2 = fmaf(h1[k], w2[k * 4 + jj], a2);
            h2[jj] = fmaxf(a2, 0.0f);
        }
        float o = b3[0];
        #pragma unroll
        for (int k = 0; k < 4; k++) o = fmaf(h2[k], w3[k], o);
        o = softplusf_(o);

        float cp = cap[l2p[(size_t)p * PATH_LEN + (t - 1)]];
        delay += o / cp;
    }
    out[p] = delay;
}

extern "C" void kernel_launch(void* const* d_in, const int* in_sizes, int n_in,
                              void* d_out, int out_size, void* d_ws, size_t ws_size,
                              hipStream_t stream)
{
    const float* flow_traffic = (const float*)d_in[0];
    const float* flow_packets = (const float*)d_in[1];
    const float* flow_pktsize = (const float*)d_in[2];
    const float* flow_type    = (const float*)d_in[3];
    const float* link_cap     = (const float*)d_in[4];
    const int*   l2p          = (const int*)d_in[5];
    const int*   p2l          = (const int*)d_in[6];
    const float* fe_w1 = (const float*)d_in[7];
    const float* fe_b1 = (const float*)d_in[8];
    const float* fe_w2 = (const float*)d_in[9];
    const float* fe_b2 = (const float*)d_in[10];
    const float* le_w1 = (const float*)d_in[11];
    const float* le_b1 = (const float*)d_in[12];
    const float* le_w2 = (const float*)d_in[13];
    const float* le_b2 = (const float*)d_in[14];
    const float* pgru_k  = (const float*)d_in[15];
    const float* pgru_rk = (const float*)d_in[16];
    const float* pgru_b  = (const float*)d_in[17];
    const float* lgru_k  = (const float*)d_in[18];
    const float* lgru_rk = (const float*)d_in[19];
    const float* lgru_b  = (const float*)d_in[20];
    const float* ro_w1 = (const float*)d_in[21];
    const float* ro_b1 = (const float*)d_in[22];
    const float* ro_w2 = (const float*)d_in[23];
    const float* ro_b2 = (const float*)d_in[24];
    const float* ro_w3 = (const float*)d_in[25];
    const float* ro_b3 = (const float*)d_in[26];
    float* out = (float*)d_out;

    char* ws = (char*)d_ws;
    unsigned short* seq  = (unsigned short*)ws;
    float*          ls   = (float*)(ws + SEQ_BYTES);
    unsigned short* lxk  = (unsigned short*)(ws + SEQ_BYTES + LS_BYTES);
    unsigned int*   p2lp = (unsigned int*)(ws + SEQ_BYTES + LS_BYTES + LXK_BYTES);

    k_pack<<<(N_LINKS * MAX_PL + 255) / 256, 256, 0, stream>>>(p2l, p2lp);
    k_init_links<<<N_LINKS, 64, 0, stream>>>(flow_traffic, link_cap, p2l,
        le_w1, le_b1, le_w2, le_b2, pgru_k, pgru_b, ls, lxk);
    k_init_paths<<<(N_PATHS + 255) / 256, 256, 0, stream>>>(flow_traffic,
        flow_packets, flow_pktsize, flow_type, fe_w1, fe_b1, fe_w2, fe_b2, seq);

    for (int it = 0; it < ITERS; ++it) {
        k_paths<<<(N_PATHS / 16 + 3) / 4, 256, 0, stream>>>(l2p, lxk,
            pgru_rk, pgru_b, seq);
        k_links<<<N_LINKS, 64, 0, stream>>>(p2lp, seq, lgru_k, lgru_rk, lgru_b,
            pgru_k, pgru_b, ls, lxk);
    }

    k_readout<<<(N_PATHS + 255) / 256, 256, 0, stream>>>(seq, l2p, link_cap,
        ro_w1, ro_b1, ro_w2, ro_b2, ro_w3, ro_b3, out);
}

// Round 4
// 637.048 us; speedup vs baseline: 11.4584x; 1.0641x over previous
//
#include <hip/hip_runtime.h>
#include <hip/hip_bf16.h>
#include <math.h>

#define N_PATHS  200000
#define PATH_LEN 8
#define N_LINKS  20000
#define MAX_PL   100
#define DIM      16
#define ITERS    8

typedef __attribute__((ext_vector_type(8))) short bf16x8;
typedef __attribute__((ext_vector_type(4))) float f32x4;

// ws layout (bytes):
//   seq  : ushort[9][N_PATHS][16]  = 57,600,000  (bf16 path_state_sequence; slot 8 = current path_state)
//   ls   : float [N_LINKS][16]     =  1,280,000  (link_state, fp32)
//   lxk  : ushort[N_LINKS][48]     =  1,920,000  (bf16: link_state @ pgru_k + pgru_b[0])
//   p2lp : uint  [N_LINKS*MAX_PL]  =  8,000,000  (packed (s<<18)|p)
#define SEQ_BYTES 57600000ull
#define LS_BYTES  1280000ull
#define LXK_BYTES 1920000ull

__device__ __forceinline__ float fast_sigmoid(float x) {
    return __builtin_amdgcn_rcpf(1.0f + __expf(-x));
}
__device__ __forceinline__ float fast_tanh(float x) {
    float ax = fabsf(x);
    float t  = __expf(-2.0f * ax);
    float r  = (1.0f - t) * __builtin_amdgcn_rcpf(1.0f + t);
    return copysignf(r, x);
}
__device__ __forceinline__ float softplusf_(float x) {
    return fmaxf(x, 0.0f) + log1pf(expf(-fabsf(x)));
}
__device__ __forceinline__ float bflo(unsigned int u) {
    union { unsigned int i; float f; } c; c.i = u << 16; return c.f;
}
__device__ __forceinline__ float bfhi(unsigned int u) {
    union { unsigned int i; float f; } c; c.i = u & 0xffff0000u; return c.f;
}
__device__ __forceinline__ unsigned int pk_bf16(float lo, float hi) {
    unsigned int r;
    asm("v_cvt_pk_bf16_f32 %0, %1, %2" : "=v"(r) : "v"(lo), "v"(hi));
    return r;
}

union U8 { unsigned int u[4]; bf16x8 v; };

// ---------------- pack p2l ----------------
__global__ __launch_bounds__(256) void k_pack(const int* __restrict__ p2l,
                                              unsigned int* __restrict__ out)
{
    int i = blockIdx.x * 256 + threadIdx.x;
    if (i < N_LINKS * MAX_PL) {
        unsigned int pi = (unsigned int)p2l[2 * i];
        unsigned int si = (unsigned int)p2l[2 * i + 1];
        out[i] = (si << 18) | pi;
    }
}

// ---------------- init: link load -> link_state -> lxk ----------------
__global__ __launch_bounds__(64) void k_init_links(
    const float* __restrict__ traffic, const float* __restrict__ cap,
    const int* __restrict__ p2l,
    const float* __restrict__ le_w1, const float* __restrict__ le_b1,
    const float* __restrict__ le_w2, const float* __restrict__ le_b2,
    const float* __restrict__ pk, const float* __restrict__ pb,
    float* __restrict__ ls, unsigned short* __restrict__ lxk)
{
    int l = blockIdx.x;
    int lane = threadIdx.x;
    float s = 0.0f;
    for (int j = lane; j < MAX_PL; j += 64) {
        int p = p2l[(size_t)(l * MAX_PL + j) * 2 + 0];
        s += traffic[p];
    }
    #pragma unroll
    for (int off = 32; off > 0; off >>= 1) s += __shfl_xor(s, off);

    float c = cap[l];
    float f0 = c * 0.1f;
    float f1 = s / (c * 1e9f);

    float h1[DIM];
    #pragma unroll
    for (int d = 0; d < DIM; d++)
        h1[d] = fmaxf(f0 * le_w1[d] + f1 * le_w1[DIM + d] + le_b1[d], 0.0f);

    float h2[DIM];
    #pragma unroll
    for (int d = 0; d < DIM; d++) {
        float a = le_b2[d];
        #pragma unroll
        for (int k = 0; k < DIM; k++) a = fmaf(h1[k], le_w2[k * DIM + d], a);
        h2[d] = fmaxf(a, 0.0f);
    }
    if (lane < DIM) ls[(size_t)l * DIM + lane] = h2[lane];
    if (lane < 48) {
        float a = pb[lane];
        #pragma unroll
        for (int k = 0; k < DIM; k++) a = fmaf(h2[k], pk[k * 48 + lane], a);
        lxk[(size_t)l * 48 + lane] = (unsigned short)(pk_bf16(a, a) & 0xffffu);
    }
}

// ---------------- init: path_state -> seq[8] (bf16) ----------------
__global__ __launch_bounds__(256) void k_init_paths(
    const float* __restrict__ traffic, const float* __restrict__ packets,
    const float* __restrict__ pktsize, const float* __restrict__ ftype,
    const float* __restrict__ fe_w1, const float* __restrict__ fe_b1,
    const float* __restrict__ fe_w2, const float* __restrict__ fe_b2,
    unsigned short* __restrict__ seq)
{
    int p = blockIdx.x * blockDim.x + threadIdx.x;
    if (p >= N_PATHS) return;
    float f[5];
    f[0] = traffic[p] * 0.0001f;
    f[1] = packets[p] * 0.01f;
    f[2] = pktsize[p] * 0.001f;
    f[3] = ftype[p * 2 + 0];
    f[4] = ftype[p * 2 + 1];

    float h1[DIM];
    #pragma unroll
    for (int d = 0; d < DIM; d++) {
        float a = fe_b1[d];
        #pragma unroll
        for (int k = 0; k < 5; k++) a = fmaf(f[k], fe_w1[k * DIM + d], a);
        h1[d] = fmaxf(a, 0.0f);
    }
    float h2[DIM];
    #pragma unroll
    for (int d = 0; d < DIM; d++) {
        float a = fe_b2[d];
        #pragma unroll
        for (int k = 0; k < DIM; k++) a = fmaf(h1[k], fe_w2[k * DIM + d], a);
        h2[d] = fmaxf(a, 0.0f);
    }
    unsigned int pkd[8];
    #pragma unroll
    for (int q = 0; q < 8; q++) pkd[q] = pk_bf16(h2[2 * q], h2[2 * q + 1]);
    uint4* out = (uint4*)(seq + ((size_t)8 * N_PATHS + p) * DIM);
    out[0] = make_uint4(pkd[0], pkd[1], pkd[2], pkd[3]);
    out[1] = make_uint4(pkd[4], pkd[5], pkd[6], pkd[7]);
}

// ---------------- per-iteration: path GRU via MFMA, 16 paths/wave ----------------
// D/C layout (16x16x32_bf16, verified m89): col=lane&15, row=(lane>>4)*4+reg.
// A/B split-K layout hedge: weights*0.5 duplicated in both halves, h in both B halves.
// All 24 lxk gathers prefetched before the step loop (indices known upfront).
__global__ __launch_bounds__(256) void k_paths(
    const int* __restrict__ l2p, const unsigned short* __restrict__ lxk,
    const float* __restrict__ rk, const float* __restrict__ b,
    unsigned short* __restrict__ seq)
{
    int l = threadIdx.x & 63;
    int wave = (blockIdx.x * 256 + threadIdx.x) >> 6;   // 0..12499
    int pr = l & 15;            // path-in-wave / D column / A row (gate col)
    int g  = l >> 4;            // 0..3
    int kq = g * 4;             // k/dim/row quad base
    int p  = wave * 16 + pr;

    // A-frags (constant): A[m=pr][k] = 0.5*rk[k&15][gate*16+pr], halves duplicated
    U8 Az, Ar, Ah;
    {
        #pragma unroll
        for (int i = 0; i < 2; i++) {
            float wz0 = rk[(kq + 2 * i) * 48 + pr] * 0.5f;
            float wz1 = rk[(kq + 2 * i + 1) * 48 + pr] * 0.5f;
            float wr0 = rk[(kq + 2 * i) * 48 + 16 + pr] * 0.5f;
            float wr1 = rk[(kq + 2 * i + 1) * 48 + 16 + pr] * 0.5f;
            float wh0 = rk[(kq + 2 * i) * 48 + 32 + pr] * 0.5f;
            float wh1 = rk[(kq + 2 * i + 1) * 48 + 32 + pr] * 0.5f;
            Az.u[i] = pk_bf16(wz0, wz1); Az.u[i + 2] = Az.u[i];
            Ar.u[i] = pk_bf16(wr0, wr1); Ar.u[i + 2] = Ar.u[i];
            Ah.u[i] = pk_bf16(wh0, wh1); Ah.u[i + 2] = Ah.u[i];
        }
    }
    // C-init = recurrent biases b[1][gate*16 + row], row = kq + reg
    f32x4 Cz, Cr, Ch;
    #pragma unroll
    for (int r = 0; r < 4; r++) {
        Cz[r] = b[48 + kq + r];
        Cr[r] = b[48 + 16 + kq + r];
        Ch[r] = b[48 + 32 + kq + r];
    }

    // l2p preload: lane holds steps {2g, 2g+1} for path p
    int2 idx2 = *(const int2*)(l2p + (size_t)p * PATH_LEN + 2 * g);

    // Prefetch ALL lxk gathers for all 8 steps (lxk is constant in this kernel).
    uint2 uzA[8], urA[8], uhA[8];
    {
        int lis[8];
        #pragma unroll
        for (int t = 0; t < 8; t++)
            lis[t] = __shfl((t & 1) ? idx2.y : idx2.x, pr + 16 * (t >> 1));
        #pragma unroll
        for (int t = 0; t < 8; t++) {
            const unsigned short* xp = lxk + (size_t)lis[t] * 48 + kq;
            uzA[t] = *(const uint2*)(xp);
            urA[t] = *(const uint2*)(xp + 16);
            uhA[t] = *(const uint2*)(xp + 32);
        }
    }

    // h from seq slot 8; copy to slot 0
    float h0, h1, h2, h3;
    U8 B;
    {
        uint2 hp = *(const uint2*)(seq + ((size_t)8 * N_PATHS + p) * DIM + kq);
        *(uint2*)(seq + (size_t)p * DIM + kq) = hp;
        h0 = bflo(hp.x); h1 = bfhi(hp.x); h2 = bflo(hp.y); h3 = bfhi(hp.y);
        B.u[0] = hp.x; B.u[1] = hp.y; B.u[2] = hp.x; B.u[3] = hp.y;
    }

    #pragma unroll
    for (int t = 0; t < PATH_LEN; t++) {
        uint2 uz = uzA[t], ur = urA[t], uh = uhA[t];

        f32x4 az = __builtin_amdgcn_mfma_f32_16x16x32_bf16(Az.v, B.v, Cz, 0, 0, 0);
        f32x4 ar = __builtin_amdgcn_mfma_f32_16x16x32_bf16(Ar.v, B.v, Cr, 0, 0, 0);
        f32x4 ah = __builtin_amdgcn_mfma_f32_16x16x32_bf16(Ah.v, B.v, Ch, 0, 0, 0);

        float mz0 = bflo(uz.x), mz1 = bfhi(uz.x), mz2 = bflo(uz.y), mz3 = bfhi(uz.y);
        float mr0 = bflo(ur.x), mr1 = bfhi(ur.x), mr2 = bflo(ur.y), mr3 = bfhi(ur.y);
        float mh0 = bflo(uh.x), mh1 = bfhi(uh.x), mh2 = bflo(uh.y), mh3 = bfhi(uh.y);

        float z0 = fast_sigmoid(mz0 + az[0]), z1 = fast_sigmoid(mz1 + az[1]);
        float z2 = fast_sigmoid(mz2 + az[2]), z3 = fast_sigmoid(mz3 + az[3]);
        float r0 = fast_sigmoid(mr0 + ar[0]), r1 = fast_sigmoid(mr1 + ar[1]);
        float r2 = fast_sigmoid(mr2 + ar[2]), r3 = fast_sigmoid(mr3 + ar[3]);
        float q0 = fast_tanh(mh0 + r0 * ah[0]), q1 = fast_tanh(mh1 + r1 * ah[1]);
        float q2 = fast_tanh(mh2 + r2 * ah[2]), q3 = fast_tanh(mh3 + r3 * ah[3]);

        h0 = z0 * h0 + (1.0f - z0) * q0;
        h1 = z1 * h1 + (1.0f - z1) * q1;
        h2 = z2 * h2 + (1.0f - z2) * q2;
        h3 = z3 * h3 + (1.0f - z3) * q3;

        unsigned int p01 = pk_bf16(h0, h1);
        unsigned int p23 = pk_bf16(h2, h3);
        *(uint2*)(seq + ((size_t)(t + 1) * N_PATHS + p) * DIM + kq) = make_uint2(p01, p23);
        B.u[0] = p01; B.u[1] = p23; B.u[2] = p01; B.u[3] = p23;
    }
}

// ---------------- per-iteration: link aggregate + link GRU + lxk ----------------
// 4 links per 256-thread block (one wave per link). Both gather rounds issued
// before any accumulation; dim-halving butterfly reduction (≈50 ops vs 192).
__device__ __forceinline__ void unpack_add(float* cur, uint4 a, uint4 c) {
    cur[0]  += bflo(a.x); cur[1]  += bfhi(a.x);
    cur[2]  += bflo(a.y); cur[3]  += bfhi(a.y);
    cur[4]  += bflo(a.z); cur[5]  += bfhi(a.z);
    cur[6]  += bflo(a.w); cur[7]  += bfhi(a.w);
    cur[8]  += bflo(c.x); cur[9]  += bfhi(c.x);
    cur[10] += bflo(c.y); cur[11] += bfhi(c.y);
    cur[12] += bflo(c.z); cur[13] += bfhi(c.z);
    cur[14] += bflo(c.w); cur[15] += bfhi(c.w);
}

__global__ __launch_bounds__(256) void k_links(
    const unsigned int* __restrict__ p2lp, const unsigned short* __restrict__ seq,
    const float* __restrict__ lk, const float* __restrict__ lrk,
    const float* __restrict__ lb,
    const float* __restrict__ pk, const float* __restrict__ pb,
    float* ls, unsigned short* __restrict__ lxk)
{
    int lane = threadIdx.x & 63;
    int l = blockIdx.x * 4 + (threadIdx.x >> 6);
    size_t base = (size_t)l * MAX_PL;

    unsigned int e0 = p2lp[base + lane];
    bool has2 = lane < (MAX_PL - 64);   // lanes 0..35 take entries 64..99
    unsigned int e1 = 0;
    if (has2) e1 = p2lp[base + 64 + lane];

    unsigned int pi0 = e0 & 0x3FFFFu, si0 = e0 >> 18;
    const uint4* g0 = (const uint4*)(seq + ((size_t)si0 * N_PATHS + pi0) * DIM);
    uint4 a0 = g0[0], c0 = g0[1];
    uint4 a1, c1;
    if (has2) {
        unsigned int pi1 = e1 & 0x3FFFFu, si1 = e1 >> 18;
        const uint4* g1 = (const uint4*)(seq + ((size_t)si1 * N_PATHS + pi1) * DIM);
        a1 = g1[0]; c1 = g1[1];
    }

    float cur[16];
    #pragma unroll
    for (int d = 0; d < 16; d++) cur[d] = 0.0f;
    unpack_add(cur, a0, c0);
    if (has2) unpack_add(cur, a1, c1);

    // dim-halving butterfly: lane ends holding full sum of dim (lane>>2)&15
    float v8[4 + 4];
    {
        int sel = (lane & 32) ? 8 : 0;
        #pragma unroll
        for (int i = 0; i < 8; i++)
            v8[i] = cur[sel + i] + __shfl_xor(cur[(8 - sel) + i], 32);
    }
    float v4[4];
    {
        int sel = (lane & 16) ? 4 : 0;
        #pragma unroll
        for (int i = 0; i < 4; i++)
            v4[i] = v8[sel + i] + __shfl_xor(v8[(4 - sel) + i], 16);
    }
    float v2[2];
    {
        int sel = (lane & 8) ? 2 : 0;
        #pragma unroll
        for (int i = 0; i < 2; i++)
            v2[i] = v4[sel + i] + __shfl_xor(v4[(2 - sel) + i], 8);
    }
    float s;
    {
        int sel = (lane & 4) ? 1 : 0;
        s = v2[sel] + __shfl_xor(v2[1 - sel], 4);
    }
    s += __shfl_xor(s, 2);
    s += __shfl_xor(s, 1);

    float accf[16];
    #pragma unroll
    for (int k = 0; k < 16; k++) accf[k] = __shfl(s, k << 2);

    float h[DIM];
    #pragma unroll
    for (int d = 0; d < DIM; d++) h[d] = ls[(size_t)l * DIM + d];

    int j = (lane < 48) ? lane : 0;
    float mx = lb[j];
    float mi = lb[48 + j];
    #pragma unroll
    for (int k = 0; k < DIM; k++) {
        mx = fmaf(accf[k], lk[k * 48 + j], mx);
        mi = fmaf(h[k],   lrk[k * 48 + j], mi);
    }

    int d = lane & 15;
    float xz = __shfl(mx, d),      rz = __shfl(mi, d);
    float xr = __shfl(mx, d + 16), rr = __shfl(mi, d + 16);
    float xh = __shfl(mx, d + 32), rh = __shfl(mi, d + 32);
    float z  = fast_sigmoid(xz + rz);
    float r  = fast_sigmoid(xr + rr);
    float hh = fast_tanh(xh + r * rh);
    float hn = z * h[d] + (1.0f - z) * hh;

    if (lane < DIM) ls[(size_t)l * DIM + lane] = hn;

    float hf[DIM];
    #pragma unroll
    for (int k = 0; k < DIM; k++) hf[k] = __shfl(hn, k);
    if (lane < 48) {
        float a = pb[lane];
        #pragma unroll
        for (int k = 0; k < DIM; k++) a = fmaf(hf[k], pk[k * 48 + lane], a);
        lxk[(size_t)l * 48 + lane] = (unsigned short)(pk_bf16(a, a) & 0xffffu);
    }
}

// ---------------- readout ----------------
__global__ __launch_bounds__(256) void k_readout(
    const unsigned short* __restrict__ seq, const int* __restrict__ l2p,
    const float* __restrict__ cap,
    const float* __restrict__ w1, const float* __restrict__ b1,
    const float* __restrict__ w2, const float* __restrict__ b2,
    const float* __restrict__ w3, const float* __restrict__ b3,
    float* __restrict__ out)
{
    int p = blockIdx.x * blockDim.x + threadIdx.x;
    if (p >= N_PATHS) return;
    float delay = 0.0f;
    for (int t = 1; t <= PATH_LEN; t++) {
        const uint4* gp = (const uint4*)(seq + ((size_t)t * N_PATHS + p) * DIM);
        uint4 a = gp[0], c = gp[1];
        float h[DIM];
        h[0]  = bflo(a.x); h[1]  = bfhi(a.x); h[2]  = bflo(a.y); h[3]  = bfhi(a.y);
        h[4]  = bflo(a.z); h[5]  = bfhi(a.z); h[6]  = bflo(a.w); h[7]  = bfhi(a.w);
        h[8]  = bflo(c.x); h[9]  = bfhi(c.x); h[10] = bflo(c.y); h[11] = bfhi(c.y);
        h[12] = bflo(c.z); h[13] = bfhi(c.z); h[14] = bflo(c.w); h[15] = bfhi(c.w);

        float h1[8];
        #pragma unroll
        for (int jj = 0; jj < 8; jj++) {
            float a1 = b1[jj];
            #pragma unroll
            for (int k = 0; k < DIM; k++) a1 = fmaf(h[k], w1[k * 8 + jj], a1);
            h1[jj] = fmaxf(a1, 0.0f);
        }
        float h2[4];
        #pragma unroll
        for (int jj = 0; jj < 4; jj++) {
            float a2 = b2[jj];
            #pragma unroll
            for (int k = 0; k < 8; k++) a2 = fmaf(h1[k], w2[k * 4 + jj], a2);
            h2[jj] = fmaxf(a2, 0.0f);
        }
        float o = b3[0];
        #pragma unroll
        for (int k = 0; k < 4; k++) o = fmaf(h2[k], w3[k], o);
        o = softplusf_(o);

        float cp = cap[l2p[(size_t)p * PATH_LEN + (t - 1)]];
        delay += o / cp;
    }
    out[p] = delay;
}

extern "C" void kernel_launch(void* const* d_in, const int* in_sizes, int n_in,
                              void* d_out, int out_size, void* d_ws, size_t ws_size,
                              hipStream_t stream)
{
    const float* flow_traffic = (const float*)d_in[0];
    const float* flow_packets = (const float*)d_in[1];
    const float* flow_pktsize = (const float*)d_in[2];
    const float* flow_type    = (const float*)d_in[3];
    const float* link_cap     = (const float*)d_in[4];
    const int*   l2p          = (const int*)d_in[5];
    const int*   p2l          = (const int*)d_in[6];
    const float* fe_w1 = (const float*)d_in[7];
    const float* fe_b1 = (const float*)d_in[8];
    const float* fe_w2 = (const float*)d_in[9];
    const float* fe_b2 = (const float*)d_in[10];
    const float* le_w1 = (const float*)d_in[11];
    const float* le_b1 = (const float*)d_in[12];
    const float* le_w2 = (const float*)d_in[13];
    const float* le_b2 = (const float*)d_in[14];
    const float* pgru_k  = (const float*)d_in[15];
    const float* pgru_rk = (const float*)d_in[16];
    const float* pgru_b  = (const float*)d_in[17];
    const float* lgru_k  = (const float*)d_in[18];
    const float* lgru_rk = (const float*)d_in[19];
    const float* lgru_b  = (const float*)d_in[20];
    const float* ro_w1 = (const float*)d_in[21];
    const float* ro_b1 = (const float*)d_in[22];
    const float* ro_w2 = (const float*)d_in[23];
    const float* ro_b2 = (const float*)d_in[24];
    const float* ro_w3 = (const float*)d_in[25];
    const float* ro_b3 = (const float*)d_in[26];
    float* out = (float*)d_out;

    char* ws = (char*)d_ws;
    unsigned short* seq  = (unsigned short*)ws;
    float*          ls   = (float*)(ws + SEQ_BYTES);
    unsigned short* lxk  = (unsigned short*)(ws + SEQ_BYTES + LS_BYTES);
    unsigned int*   p2lp = (unsigned int*)(ws + SEQ_BYTES + LS_BYTES + LXK_BYTES);

    k_pack<<<(N_LINKS * MAX_PL + 255) / 256, 256, 0, stream>>>(p2l, p2lp);
    k_init_links<<<N_LINKS, 64, 0, stream>>>(flow_traffic, link_cap, p2l,
        le_w1, le_b1, le_w2, le_b2, pgru_k, pgru_b, ls, lxk);
    k_init_paths<<<(N_PATHS + 255) / 256, 256, 0, stream>>>(flow_traffic,
        flow_packets, flow_pktsize, flow_type, fe_w1, fe_b1, fe_w2, fe_b2, seq);

    for (int it = 0; it < ITERS; ++it) {
        k_paths<<<(N_PATHS / 16 + 3) / 4, 256, 0, stream>>>(l2p, lxk,
            pgru_rk, pgru_b, seq);
        if (it != ITERS - 1)   // final link GRU is dead: output uses only seq
            k_links<<<N_LINKS / 4, 256, 0, stream>>>(p2lp, seq, lgru_k, lgru_rk,
                lgru_b, pgru_k, pgru_b, ls, lxk);
    }

    k_readout<<<(N_PATHS + 255) / 256, 256, 0, stream>>>(seq, l2p, link_cap,
        ro_w1, ro_b1, ro_w2, ro_b2, ro_w3, ro_b3, out);
}